// Round 11
// baseline (280.205 us; speedup 1.0000x reference)
//
#include <hip/hip_runtime.h>

#define NSTEP 2047

typedef float v2f __attribute__((ext_vector_type(2), aligned(8)));

__device__ __forceinline__ float fexp2(float x){float r;asm("v_exp_f32 %0, %1":"=v"(r):"v"(x));return r;}
__device__ __forceinline__ float frcp (float x){float r;asm("v_rcp_f32 %0, %1":"=v"(r):"v"(x));return r;}

// 32 chunks, wave-uniform. chunk 0: exact from t=1, 70 blocks (560 steps),
// acc t=1..558 (last block: 6 acc + 2 dead). chunk c>=1: t_s = 48c+47,
// 64 blocks (512 steps) = 58 warm + 6 acc; acc t in [48c+511, 48c+558].
// chunk 31: acc t=1999..2045, then t=2046 (no acc) -> x_T snapshot.
__global__ __launch_bounds__(64, 2)
void cstr_chunk(const float* __restrict__ w, const float* __restrict__ Kp,
                const float* __restrict__ Lp, const float* __restrict__ Mp,
                const float* __restrict__ Mop, float* __restrict__ ws)
{
    const int lane = threadIdx.x;
    const int wid  = blockIdx.x;               // 2048 waves
    const int c    = wid & 31;                 // chunk (wave-uniform)
    const int b    = (wid >> 5) * 64 + lane;   // sample 0..4095

    constexpr float Hc=0.01f, Acf=0.99f, Bcf=-0.5f*Hc*Hc;
    constexpr float T2L=2.8853900817779268f, L2E=1.4426950408889634f;
    constexpr float SC1=0.5f*Hc, SCT=SC1*T2L;

    const float K0=Kp[0], K1=Kp[1], MoV=Mop[0];
    const float c00=Lp[0], c11=Lp[5], c22=Lp[10], c33=Lp[15];
    const float c01=Lp[1]+Lp[4], c02=Lp[2]+Lp[8], c03=Lp[3]+Lp[12];
    const float c12=Lp[6]+Lp[9], c13=Lp[7]+Lp[13], c23=Lp[11]+Lp[14];
    const float m0=Mp[0], m1=Mp[1], m2=Mp[2], m3=Mp[3];
    const float sB = MoV * L2E;

    const int t_s = (c == 0) ? 1 : 48*c + 47;  // start t; t_s-1 even for all c

    const float* rw0 = w + (size_t)b * (2*NSTEP);
    const float* rw1 = rw0 + NSTEP;

    const float w10 = rw0[0], w20 = rw1[0];
    const float th1 = 1.0f - 2.0f*frcp(fexp2(T2L) + 1.0f);   // tanh(1)

    // ---- state init ----
    float x1, x2, xh1, U, THh1;
    if (c == 0) {
        x1 = Acf + Hc*SC1 + Hc*K0 + w10;
        x2 = Bcf - Hc*th1 + 0.5f*Hc*K0 + w20;
        xh1 = 1.0f; U = K0; THh1 = th1;
    } else { x1 = 0.0f; x2 = 0.0f; xh1 = 0.0f; U = 0.0f; THh1 = 0.0f; }
    float xh2 = 0.0f;
    float THh2 = 1.0f - 2.0f*frcp(fexp2(SCT) + 1.0f);
    float THx1 = 1.0f - 2.0f*frcp(fexp2(T2L*x1) + 1.0f);
    float THx2 = 1.0f - 2.0f*frcp(fexp2(__builtin_fmaf(T2L,x2,SCT)) + 1.0f);
    float delta = 0.5f, PS = 0.0f;
    float SXX1=0.0f, SXX2=0.0f, SXY=0.0f, SD=0.0f;

    auto step = [&](float w1v, float w2v, bool acc, bool exact) {
        const float hu = Hc*U;
        const float f1 = __builtin_fmaf(Acf, xh1, __builtin_fmaf(Hc, THh2, hu));
        const float f2 = __builtin_fmaf(Acf, xh2, __builtin_fmaf(-Hc, THh1,
                          __builtin_fmaf(0.5f, hu, Bcf)));
        float g1 = __builtin_fmaf(c00,x1,m0); g1=__builtin_fmaf(c01,x2,g1);
        g1=__builtin_fmaf(c02,f1,g1); g1=__builtin_fmaf(c03,f2,g1);
        float g2 = __builtin_fmaf(c11,x2,m1); g2=__builtin_fmaf(c12,f1,g2);
        g2=__builtin_fmaf(c13,f2,g2);
        float g3 = __builtin_fmaf(c22,f1,m2); g3=__builtin_fmaf(c23,f2,g3);
        float g4 = __builtin_fmaf(c33,f2,m3);
        const float ps = __builtin_fmaf(x1,g1, __builtin_fmaf(x2,g2,
                          __builtin_fmaf(f1,g3, f2*g4)));
        if (exact) {
            delta = frcp(1.0f + fexp2(__builtin_fmaf(-L2E, ps, -sB)));
        } else {
            const float dphi = ps - PS;
            const float sd = __builtin_fmaf(-delta, delta, delta);
            const float qq = __builtin_fmaf(dphi, 0.5f - delta, 1.0f);
            delta = __builtin_fmaf(dphi*sd, qq, delta);
        }
        PS = ps;
        const float d1 = x1 - f1, d2 = x2 - f2;
        const float nh1 = __builtin_fmaf(delta, d1, f1);
        const float nh2 = __builtin_fmaf(delta, d2, f2);
        const float un  = __builtin_fmaf(K1, nh2, K0*nh1);
        if (acc) {
            SXX1 = __builtin_fmaf(x1, x1, SXX1);
            SXX2 = __builtin_fmaf(x2, x2, SXX2);
            SXY  = __builtin_fmaf(x1, x2, SXY);
            SD  += delta;
        }
        const float hun = Hc*un;
        const float nx1 = __builtin_fmaf(Acf, x1, __builtin_fmaf(Hc, THx2, w1v + hun));
        const float nx2 = __builtin_fmaf(Acf, x2, __builtin_fmaf(-Hc, THx1,
                           __builtin_fmaf(0.5f, hun, w2v + Bcf)));
        if (exact) {
            THh1 = __builtin_fmaf(-2.0f, frcp(fexp2(T2L*nh1)+1.0f), 1.0f);
            THh2 = __builtin_fmaf(-2.0f, frcp(fexp2(__builtin_fmaf(T2L,nh2,SCT))+1.0f), 1.0f);
            THx1 = __builtin_fmaf(-2.0f, frcp(fexp2(T2L*nx1)+1.0f), 1.0f);
            THx2 = __builtin_fmaf(-2.0f, frcp(fexp2(__builtin_fmaf(T2L,nx2,SCT))+1.0f), 1.0f);
        } else {
            { const float dS=nh1-xh1, sc=__builtin_fmaf(-THh1,THh1,1.0f);
              THh1=__builtin_fmaf(dS*sc, __builtin_fmaf(-dS,THh1,1.0f), THh1); }
            { const float dS=nh2-xh2, sc=__builtin_fmaf(-THh2,THh2,1.0f);
              THh2=__builtin_fmaf(dS*sc, __builtin_fmaf(-dS,THh2,1.0f), THh2); }
            { const float dS=nx1-x1,  sc=__builtin_fmaf(-THx1,THx1,1.0f);
              THx1=__builtin_fmaf(dS*sc, __builtin_fmaf(-dS,THx1,1.0f), THx1); }
            { const float dS=nx2-x2,  sc=__builtin_fmaf(-THx2,THx2,1.0f);
              THx2=__builtin_fmaf(dS*sc, __builtin_fmaf(-dS,THx2,1.0f), THx2); }
        }
        x1=nx1; x2=nx2; xh1=nh1; xh2=nh2; U=un;
    };

    // ---- rolling float2 stream: regs hold pairs covering [o, o+9] ----
    const int o0 = t_s - 1;                    // even
    const float* q0 = rw0 + o0;
    const float* q1 = rw1 + o0;
    v2f A0=*(const v2f*)(q0),   A1=*(const v2f*)(q0+2), A2=*(const v2f*)(q0+4),
        A3=*(const v2f*)(q0+6), A4=*(const v2f*)(q0+8);
    v2f B0=*(const v2f*)(q1),   B1=*(const v2f*)(q1+2), B2=*(const v2f*)(q1+4),
        B3=*(const v2f*)(q1+6), B4=*(const v2f*)(q1+8);
    const float* p0 = q0 + 10;
    const float* p1 = q1 + 10;

    auto runblk = [&](bool ACC) {   // 8 steps + next-block prefetch
        const v2f Na1=*(const v2f*)(p0),   Na2=*(const v2f*)(p0+2),
                  Na3=*(const v2f*)(p0+4), Na4=*(const v2f*)(p0+6);
        const v2f Nb1=*(const v2f*)(p1),   Nb2=*(const v2f*)(p1+2),
                  Nb3=*(const v2f*)(p1+4), Nb4=*(const v2f*)(p1+6);
        step(A0.y, B0.y, ACC, true );
        step(A1.x, B1.x, ACC, false);
        step(A1.y, B1.y, ACC, false);
        step(A2.x, B2.x, ACC, false);
        step(A2.y, B2.y, ACC, false);
        step(A3.x, B3.x, ACC, false);
        step(A3.y, B3.y, ACC, false);
        step(A4.x, B4.x, ACC, false);
        A0=A4; A1=Na1; A2=Na2; A3=Na3; A4=Na4;
        B0=B4; B1=Nb1; B2=Nb2; B3=Nb3; B4=Nb4;
        p0 += 8; p1 += 8;
    };

    if (c == 0) {
        for (int g = 0; g < 69; ++g) runblk(true);   // t = 1..552
        // block 69 from regs: t = 553..560, acc first 6 (t<=558)
        step(A0.y, B0.y, true , true );
        step(A1.x, B1.x, true , false);
        step(A1.y, B1.y, true , false);
        step(A2.x, B2.x, true , false);
        step(A2.y, B2.y, true , false);
        step(A3.x, B3.x, true , false);
        step(A3.y, B3.y, false, false);
        step(A4.x, B4.x, false, false);
    } else {
        for (int g = 0; g < 58; ++g) runblk(false);  // warm: t_s .. t_s+463
        for (int g = 0; g < 4;  ++g) runblk(true);   // acc blocks 58..61
        // block 62 from regs (acc): t = t_s+496 .. t_s+503
        step(A0.y, B0.y, true, true );
        step(A1.x, B1.x, true, false);
        step(A1.y, B1.y, true, false);
        step(A2.x, B2.x, true, false);
        step(A2.y, B2.y, true, false);
        step(A3.x, B3.x, true, false);
        step(A3.y, B3.y, true, false);
        step(A4.x, B4.x, true, false);
    }

    // final peeled block (c==0 handled above; for c>=1): words o0+505..o0+512,
    // t = t_s+504 .. t_s+511 (chunk 31: 2039..2046, all in-bounds).
    float xt1 = x1, xt2 = x2;
    if (c != 0) {
        float fa[8], fb[8];
#pragma unroll
        for (int j = 0; j < 8; ++j) { fa[j] = rw0[o0+505+j]; fb[j] = rw1[o0+505+j]; }
        const bool late = (c == 31);
        step(fa[0], fb[0], true, true );
        step(fa[1], fb[1], true, false);
        step(fa[2], fb[2], true, false);
        step(fa[3], fb[3], true, false);
        step(fa[4], fb[4], true, false);
        step(fa[5], fb[5], true, false);
        step(fa[6], fb[6], true, false);
        step(fa[7], fb[7], !late, false);   // chunk31: t=2046, no acc
        xt1 = x1; xt2 = x2;                 // chunk31: x_T
    }

    // per-chunk partial cost -> ws[c][b]
    float P = SXX1 + SXX2 + SD;
    P = __builtin_fmaf(K0*K0, SXX1, P);
    P = __builtin_fmaf(2.0f*K0*K1, SXY, P);
    P = __builtin_fmaf(K1*K1, SXX2, P);
    if (c == 0)  P += 2.0f + K0*K0;                 // t=0 terms
    if (c == 31) P += 10.0f * (xt1*xt1 + xt2*xt2);  // final cost
    ws[c * 4096 + b] = P;
}

__global__ __launch_bounds__(64)
void cstr_reduce(const float* __restrict__ ws, float* __restrict__ out)
{
    const int b = blockIdx.x * 64 + threadIdx.x;   // 0..4095
    float s = 0.0f;
#pragma unroll
    for (int c = 0; c < 32; ++c) s += ws[c * 4096 + b];
    out[b] = s;
}

extern "C" void kernel_launch(void* const* d_in, const int* in_sizes, int n_in,
                              void* d_out, int out_size, void* d_ws, size_t ws_size,
                              hipStream_t stream) {
    const float* w  = (const float*)d_in[0];
    const float* K  = (const float*)d_in[1];
    const float* L  = (const float*)d_in[2];
    const float* M  = (const float*)d_in[3];
    const float* Mo = (const float*)d_in[4];
    float* out = (float*)d_out;
    float* ws  = (float*)d_ws;                     // 32*4096*4 B = 512 KB
    cstr_chunk <<<dim3(2048), dim3(64), 0, stream>>>(w, K, L, M, Mo, ws);
    cstr_reduce<<<dim3(64),   dim3(64), 0, stream>>>(ws, out);
}

// Round 12
// 128.331 us; speedup vs baseline: 2.1835x; 2.1835x over previous
//
#include <hip/hip_runtime.h>

#define NSTEP 2047

typedef float v2f  __attribute__((ext_vector_type(2)));
typedef float v2fa __attribute__((ext_vector_type(2), aligned(8)));

__device__ __forceinline__ float fexp2(float x){float r;asm("v_exp_f32 %0, %1":"=v"(r):"v"(x));return r;}
__device__ __forceinline__ float frcp (float x){float r;asm("v_rcp_f32 %0, %1":"=v"(r):"v"(x));return r;}
__device__ __forceinline__ v2f pk_fma(v2f a, v2f b, v2f c){
    v2f d; asm("v_pk_fma_f32 %0, %1, %2, %3":"=v"(d):"v"(a),"v"(b),"v"(c)); return d;
}
__device__ __forceinline__ v2f pk_mul(v2f a, v2f b){
    v2f d; asm("v_pk_mul_f32 %0, %1, %2":"=v"(d):"v"(a),"v"(b)); return d;
}

// 16 chunks, window 128. c=0..3: exact from t=1 (no seed error), warm 16c
// blocks, acc 16 blocks -> t in [128c+1, 128c+128]. c=4..14: t_s=128c-471,
// zero seed, warm 59 blocks (472), acc 16 blocks. c=15: t_s=1449, warm 59,
// acc t=1921..2045, then t=2046 (no acc) -> x_T snapshot.
__global__ __launch_bounds__(64, 1)
void cstr_chunk(const float* __restrict__ w, const float* __restrict__ Kp,
                const float* __restrict__ Lp, const float* __restrict__ Mp,
                const float* __restrict__ Mop, float* __restrict__ ws)
{
    const int lane = threadIdx.x;
    const int wid  = blockIdx.x;               // 1024 waves
    const int c    = wid & 15;                 // chunk (wave-uniform)
    const int b    = (wid >> 4) * 64 + lane;   // sample 0..4095

    constexpr float Hc=0.01f, Acf=0.99f, Bcf=-0.5f*Hc*Hc;
    constexpr float T2L=2.8853900817779268f, L2E=1.4426950408889634f;
    constexpr float SC1=0.5f*Hc, SCT=SC1*T2L;

    const float K0=Kp[0], K1=Kp[1], MoV=Mop[0];
    const float c00=Lp[0], c11=Lp[5], c22=Lp[10], c33=Lp[15];
    const float c01=Lp[1]+Lp[4], c02=Lp[2]+Lp[8], c03=Lp[3]+Lp[12];
    const float c12=Lp[6]+Lp[9], c13=Lp[7]+Lp[13], c23=Lp[11]+Lp[14];
    const float m0=Mp[0], m1=Mp[1], m2=Mp[2], m3=Mp[3];
    const float sB = MoV * L2E;

    const bool exact0 = (c <= 3);
    const int  t_s = exact0 ? 1 : 128*c - 471;     // odd -> o0 even
    const int  o0  = t_s - 1;

    const float* rw0 = w + (size_t)b * (2*NSTEP);
    const float* rw1 = rw0 + NSTEP;

    const float w10 = rw0[0], w20 = rw1[0];
    const float th1 = 1.0f - 2.0f*frcp(fexp2(T2L) + 1.0f);     // tanh(1)
    const float thS = 1.0f - 2.0f*frcp(fexp2(SCT) + 1.0f);     // tanh(H/2)

    // ---- state (packed pairs) ----
    v2f X, XH, THH, THX;
    float U;
    if (exact0) {
        X.x = Acf + Hc*SC1 + Hc*K0 + w10;
        X.y = Bcf - Hc*th1 + 0.5f*Hc*K0 + w20;
        XH  = (v2f){1.0f, 0.0f};
        THH = (v2f){th1, thS};
        U   = K0;
    } else {
        X = (v2f){0.0f, 0.0f}; XH = (v2f){0.0f, 0.0f};
        THH = (v2f){0.0f, thS}; U = 0.0f;
    }
    THX.x = 1.0f - 2.0f*frcp(fexp2(T2L*X.x) + 1.0f);
    THX.y = 1.0f - 2.0f*frcp(fexp2(__builtin_fmaf(T2L,X.y,SCT)) + 1.0f);
    float delta = 0.5f, PS = 0.0f;
    v2f SXX = (v2f){0.0f, 0.0f};
    float SXY = 0.0f, SD = 0.0f;

    const v2f ONE2 = (v2f){ 1.0f,  1.0f};
    const v2f NEG1 = (v2f){-1.0f, -1.0f};

    auto step = [&](float w1v, float w2v, bool acc, bool exact) {
        const float hu = Hc*U;
        const float f1 = __builtin_fmaf(Acf, XH.x, __builtin_fmaf(Hc, THH.y, hu));
        const float f2 = __builtin_fmaf(Acf, XH.y, __builtin_fmaf(-Hc, THH.x,
                          __builtin_fmaf(0.5f, hu, Bcf)));
        const v2f F = (v2f){f1, f2};
        float g1 = __builtin_fmaf(c00,X.x,m0); g1=__builtin_fmaf(c01,X.y,g1);
        g1=__builtin_fmaf(c02,f1,g1); g1=__builtin_fmaf(c03,f2,g1);
        float g2 = __builtin_fmaf(c11,X.y,m1); g2=__builtin_fmaf(c12,f1,g2);
        g2=__builtin_fmaf(c13,f2,g2);
        float g3 = __builtin_fmaf(c22,f1,m2); g3=__builtin_fmaf(c23,f2,g3);
        float g4 = __builtin_fmaf(c33,f2,m3);
        const float ps = __builtin_fmaf(X.x,g1, __builtin_fmaf(X.y,g2,
                          __builtin_fmaf(f1,g3, f2*g4)));
        if (exact) {
            delta = frcp(1.0f + fexp2(__builtin_fmaf(-L2E, ps, -sB)));
        } else {
            const float dphi = ps - PS;
            const float sd = __builtin_fmaf(-delta, delta, delta);
            const float qq = __builtin_fmaf(dphi, 0.5f - delta, 1.0f);
            delta = __builtin_fmaf(dphi*sd, qq, delta);
        }
        PS = ps;
        const v2f D   = pk_fma(F, NEG1, X);            // (x1-f1, x2-f2)
        const v2f DL2 = (v2f){delta, delta};
        const v2f NH  = pk_fma(DL2, D, F);
        const float un = __builtin_fmaf(K1, NH.y, K0*NH.x);
        if (acc) {
            SXX = pk_fma(X, X, SXX);
            SXY = __builtin_fmaf(X.x, X.y, SXY);
            SD += delta;
        }
        const float hun = Hc*un;
        v2f XN;
        XN.x = __builtin_fmaf(Acf, X.x, __builtin_fmaf(Hc, THX.y, w1v + hun));
        XN.y = __builtin_fmaf(Acf, X.y, __builtin_fmaf(-Hc, THX.x,
                __builtin_fmaf(0.5f, hun, w2v + Bcf)));
        if (exact) {
            THH.x = __builtin_fmaf(-2.0f, frcp(fexp2(T2L*NH.x)+1.0f), 1.0f);
            THH.y = __builtin_fmaf(-2.0f, frcp(fexp2(__builtin_fmaf(T2L,NH.y,SCT))+1.0f), 1.0f);
            THX.x = __builtin_fmaf(-2.0f, frcp(fexp2(T2L*XN.x)+1.0f), 1.0f);
            THX.y = __builtin_fmaf(-2.0f, frcp(fexp2(__builtin_fmaf(T2L,XN.y,SCT))+1.0f), 1.0f);
        } else {
            {   // packed 2nd-order tanh propagation: TH += dS*(1-TH^2)*(1-dS*TH)
                const v2f dS = pk_fma(XH, NEG1, NH);
                const v2f t2 = pk_mul(THH, THH);
                const v2f sc = pk_fma(t2, NEG1, ONE2);
                const v2f mq = pk_mul(dS, THH);
                const v2f q2 = pk_fma(mq, NEG1, ONE2);
                const v2f pp = pk_mul(dS, sc);
                THH = pk_fma(pp, q2, THH);
            }
            {
                const v2f dS = pk_fma(X, NEG1, XN);
                const v2f t2 = pk_mul(THX, THX);
                const v2f sc = pk_fma(t2, NEG1, ONE2);
                const v2f mq = pk_mul(dS, THX);
                const v2f q2 = pk_fma(mq, NEG1, ONE2);
                const v2f pp = pk_mul(dS, sc);
                THX = pk_fma(pp, q2, THX);
            }
        }
        X = XN; XH = NH; U = un;
    };

    // ---- rolling float2 stream: regs hold words [o, o+9], advance by 8 ----
    const float* q0 = rw0 + o0;
    const float* q1 = rw1 + o0;
    v2fa A0=*(const v2fa*)(q0),   A1=*(const v2fa*)(q0+2), A2=*(const v2fa*)(q0+4),
         A3=*(const v2fa*)(q0+6), A4=*(const v2fa*)(q0+8);
    v2fa B0=*(const v2fa*)(q1),   B1=*(const v2fa*)(q1+2), B2=*(const v2fa*)(q1+4),
         B3=*(const v2fa*)(q1+6), B4=*(const v2fa*)(q1+8);
    const float* p0 = q0 + 10;
    const float* p1 = q1 + 10;

    auto runblk = [&](bool ACC) {   // 8 steps + next-block prefetch
        const v2fa Na1=*(const v2fa*)(p0),   Na2=*(const v2fa*)(p0+2),
                   Na3=*(const v2fa*)(p0+4), Na4=*(const v2fa*)(p0+6);
        const v2fa Nb1=*(const v2fa*)(p1),   Nb2=*(const v2fa*)(p1+2),
                   Nb3=*(const v2fa*)(p1+4), Nb4=*(const v2fa*)(p1+6);
        step(A0.y, B0.y, ACC, true );
        step(A1.x, B1.x, ACC, false);
        step(A1.y, B1.y, ACC, false);
        step(A2.x, B2.x, ACC, false);
        step(A2.y, B2.y, ACC, false);
        step(A3.x, B3.x, ACC, false);
        step(A3.y, B3.y, ACC, false);
        step(A4.x, B4.x, ACC, false);
        A0=A4; A1=Na1; A2=Na2; A3=Na3; A4=Na4;
        B0=B4; B1=Nb1; B2=Nb2; B3=Nb3; B4=Nb4;
        p0 += 8; p1 += 8;
    };

#define BLK8_REGS(ACC) \
    step(A0.y, B0.y, ACC, true ); \
    step(A1.x, B1.x, ACC, false); \
    step(A1.y, B1.y, ACC, false); \
    step(A2.x, B2.x, ACC, false); \
    step(A2.y, B2.y, ACC, false); \
    step(A3.x, B3.x, ACC, false); \
    step(A3.y, B3.y, ACC, false); \
    step(A4.x, B4.x, ACC, false);

    float xt1 = 0.0f, xt2 = 0.0f;
    if (c <= 3) {
        for (int g = 0; g < 16*c; ++g) runblk(false);   // exact warm (c>0)
        for (int g = 0; g < 16;   ++g) runblk(true);    // acc t in [128c+1, 128c+128]
    } else if (c <= 14) {
        for (int g = 0; g < 59; ++g) runblk(false);     // seed warm 472
        for (int g = 0; g < 15; ++g) runblk(true);      // acc blocks 59..73
        BLK8_REGS(true)                                  // block 74 from regs
    } else {  // c == 15, t_s = 1449
        for (int g = 0; g < 59; ++g) runblk(false);
        for (int g = 0; g < 14; ++g) runblk(true);      // t = 1921..2032
        BLK8_REGS(true)                                  // t = 2033..2040
        // scalar peel: t = 2041..2046 (words 2041..2046, in-bounds)
        float fa[6], fb[6];
#pragma unroll
        for (int j = 0; j < 6; ++j) { fa[j] = rw0[2041+j]; fb[j] = rw1[2041+j]; }
        step(fa[0], fb[0], true,  true );
        step(fa[1], fb[1], true,  false);
        step(fa[2], fb[2], true,  false);
        step(fa[3], fb[3], true,  false);
        step(fa[4], fb[4], true,  false);
        step(fa[5], fb[5], false, false);   // t=2046: no acc
        xt1 = X.x; xt2 = X.y;               // x_T
    }

    // per-chunk partial cost -> ws[c][b]
    float P = SXX.x + SXX.y + SD;
    P = __builtin_fmaf(K0*K0, SXX.x, P);
    P = __builtin_fmaf(2.0f*K0*K1, SXY, P);
    P = __builtin_fmaf(K1*K1, SXX.y, P);
    if (c == 0)  P += 2.0f + K0*K0;                 // t=0 terms
    if (c == 15) P += 10.0f * (xt1*xt1 + xt2*xt2);  // final cost
    ws[c * 4096 + b] = P;
#undef BLK8_REGS
}

__global__ __launch_bounds__(64)
void cstr_reduce(const float* __restrict__ ws, float* __restrict__ out)
{
    const int b = blockIdx.x * 64 + threadIdx.x;   // 0..4095
    float s = 0.0f;
#pragma unroll
    for (int c = 0; c < 16; ++c) s += ws[c * 4096 + b];
    out[b] = s;
}

extern "C" void kernel_launch(void* const* d_in, const int* in_sizes, int n_in,
                              void* d_out, int out_size, void* d_ws, size_t ws_size,
                              hipStream_t stream) {
    const float* w  = (const float*)d_in[0];
    const float* K  = (const float*)d_in[1];
    const float* L  = (const float*)d_in[2];
    const float* M  = (const float*)d_in[3];
    const float* Mo = (const float*)d_in[4];
    float* out = (float*)d_out;
    float* ws  = (float*)d_ws;                     // 16*4096*4 B = 256 KB
    cstr_chunk <<<dim3(1024), dim3(64), 0, stream>>>(w, K, L, M, Mo, ws);
    cstr_reduce<<<dim3(64),   dim3(64), 0, stream>>>(ws, out);
}

// Round 13
// 82.812 us; speedup vs baseline: 3.3836x; 1.5497x over previous
//
#include <hip/hip_runtime.h>

#define NSTEP 2047

typedef float v4f __attribute__((ext_vector_type(4), aligned(4)));

__device__ __forceinline__ float fexp2(float x){float r;asm("v_exp_f32 %0, %1":"=v"(r):"v"(x));return r;}
__device__ __forceinline__ float frcp (float x){float r;asm("v_rcp_f32 %0, %1":"=v"(r):"v"(x));return r;}

// 16 chunks, balanced. Warm W = 464 (58 blocks; r11-proven).
// c=0: exact from t=1, acc t=1..480 (60 blocks). Cost 480.
// c=1..15: t_s = 104c-87, zero seed, warm 58 blocks, acc 13 blocks
//   -> window t in [104c+377 .. 104c+480]. Cost 568.
// c=15: + tail t=2041..2045 (acc) and t=2046 (no acc) -> x_T. Cost 574.
__global__ __launch_bounds__(64, 1)
void cstr_chunk(const float* __restrict__ w, const float* __restrict__ Kp,
                const float* __restrict__ Lp, const float* __restrict__ Mp,
                const float* __restrict__ Mop, float* __restrict__ ws)
{
    const int lane = threadIdx.x;
    const int wid  = blockIdx.x;               // 1024 waves
    const int c    = wid & 15;                 // chunk (wave-uniform)
    const int b    = (wid >> 4) * 64 + lane;   // sample 0..4095

    constexpr float Hc=0.01f, Acf=0.99f, Bcf=-0.5f*Hc*Hc;
    constexpr float T2L=2.8853900817779268f, L2E=1.4426950408889634f;
    constexpr float SC1=0.5f*Hc, SCT=SC1*T2L;

    const float K0=Kp[0], K1=Kp[1], MoV=Mop[0];
    const float c00=Lp[0], c11=Lp[5], c22=Lp[10], c33=Lp[15];
    const float c01=Lp[1]+Lp[4], c02=Lp[2]+Lp[8], c03=Lp[3]+Lp[12];
    const float c12=Lp[6]+Lp[9], c13=Lp[7]+Lp[13], c23=Lp[11]+Lp[14];
    const float m0=Mp[0], m1=Mp[1], m2=Mp[2], m3=Mp[3];
    const float sB = MoV * L2E;

    const int t_s = (c == 0) ? 1 : 104*c - 87;   // o0 = t_s-1 == 0 mod 8
    const int o0  = t_s - 1;

    const float* rw0 = w + (size_t)b * (2*NSTEP);
    const float* rw1 = rw0 + NSTEP;

    const float w10 = rw0[0], w20 = rw1[0];
    const float th1 = 1.0f - 2.0f*frcp(fexp2(T2L) + 1.0f);   // tanh(1)

    // ---- state init ----
    float x1, x2, xh1, U, THh1;
    if (c == 0) {
        x1 = Acf + Hc*SC1 + Hc*K0 + w10;
        x2 = Bcf - Hc*th1 + 0.5f*Hc*K0 + w20;
        xh1 = 1.0f; U = K0; THh1 = th1;
    } else { x1 = 0.0f; x2 = 0.0f; xh1 = 0.0f; U = 0.0f; THh1 = 0.0f; }
    float xh2 = 0.0f;
    float THh2 = 1.0f - 2.0f*frcp(fexp2(SCT) + 1.0f);
    float THx1 = 1.0f - 2.0f*frcp(fexp2(T2L*x1) + 1.0f);
    float THx2 = 1.0f - 2.0f*frcp(fexp2(__builtin_fmaf(T2L,x2,SCT)) + 1.0f);
    float delta = 0.5f, PS = 0.0f;
    float SXX1=0.0f, SXX2=0.0f, SXY=0.0f, SD=0.0f;

    auto step = [&](float w1v, float w2v, bool acc, bool exact) {
        const float hu = Hc*U;
        const float f1 = __builtin_fmaf(Acf, xh1, __builtin_fmaf(Hc, THh2, hu));
        const float f2 = __builtin_fmaf(Acf, xh2, __builtin_fmaf(-Hc, THh1,
                          __builtin_fmaf(0.5f, hu, Bcf)));
        float g1 = __builtin_fmaf(c00,x1,m0); g1=__builtin_fmaf(c01,x2,g1);
        g1=__builtin_fmaf(c02,f1,g1); g1=__builtin_fmaf(c03,f2,g1);
        float g2 = __builtin_fmaf(c11,x2,m1); g2=__builtin_fmaf(c12,f1,g2);
        g2=__builtin_fmaf(c13,f2,g2);
        float g3 = __builtin_fmaf(c22,f1,m2); g3=__builtin_fmaf(c23,f2,g3);
        float g4 = __builtin_fmaf(c33,f2,m3);
        const float ps = __builtin_fmaf(x1,g1, __builtin_fmaf(x2,g2,
                          __builtin_fmaf(f1,g3, f2*g4)));
        if (exact) {
            delta = frcp(1.0f + fexp2(__builtin_fmaf(-L2E, ps, -sB)));
        } else {
            const float dphi = ps - PS;
            const float sd = __builtin_fmaf(-delta, delta, delta);
            const float qq = __builtin_fmaf(dphi, 0.5f - delta, 1.0f);
            delta = __builtin_fmaf(dphi*sd, qq, delta);
        }
        PS = ps;
        const float d1 = x1 - f1, d2 = x2 - f2;
        const float nh1 = __builtin_fmaf(delta, d1, f1);
        const float nh2 = __builtin_fmaf(delta, d2, f2);
        const float un  = __builtin_fmaf(K1, nh2, K0*nh1);
        if (acc) {
            SXX1 = __builtin_fmaf(x1, x1, SXX1);
            SXX2 = __builtin_fmaf(x2, x2, SXX2);
            SXY  = __builtin_fmaf(x1, x2, SXY);
            SD  += delta;
        }
        const float hun = Hc*un;
        const float nx1 = __builtin_fmaf(Acf, x1, __builtin_fmaf(Hc, THx2, w1v + hun));
        const float nx2 = __builtin_fmaf(Acf, x2, __builtin_fmaf(-Hc, THx1,
                           __builtin_fmaf(0.5f, hun, w2v + Bcf)));
        if (exact) {
            THh1 = __builtin_fmaf(-2.0f, frcp(fexp2(T2L*nh1)+1.0f), 1.0f);
            THh2 = __builtin_fmaf(-2.0f, frcp(fexp2(__builtin_fmaf(T2L,nh2,SCT))+1.0f), 1.0f);
            THx1 = __builtin_fmaf(-2.0f, frcp(fexp2(T2L*nx1)+1.0f), 1.0f);
            THx2 = __builtin_fmaf(-2.0f, frcp(fexp2(__builtin_fmaf(T2L,nx2,SCT))+1.0f), 1.0f);
        } else {
            { const float dS=nh1-xh1, sc=__builtin_fmaf(-THh1,THh1,1.0f);
              THh1=__builtin_fmaf(dS*sc, __builtin_fmaf(-dS,THh1,1.0f), THh1); }
            { const float dS=nh2-xh2, sc=__builtin_fmaf(-THh2,THh2,1.0f);
              THh2=__builtin_fmaf(dS*sc, __builtin_fmaf(-dS,THh2,1.0f), THh2); }
            { const float dS=nx1-x1,  sc=__builtin_fmaf(-THx1,THx1,1.0f);
              THx1=__builtin_fmaf(dS*sc, __builtin_fmaf(-dS,THx1,1.0f), THx1); }
            { const float dS=nx2-x2,  sc=__builtin_fmaf(-THx2,THx2,1.0f);
              THx2=__builtin_fmaf(dS*sc, __builtin_fmaf(-dS,THx2,1.0f), THx2); }
        }
        x1=nx1; x2=nx2; xh1=nh1; xh2=nh2; U=un;
    };

    // ---- rolling 16B float4 stream: regs hold words [o..o+11], advance 8 ----
    const float* q0 = rw0 + o0;
    const float* q1 = rw1 + o0;
    v4f Wa0 = *(const v4f*)(q0);     v4f Wb0 = *(const v4f*)(q1);
    v4f Wa1 = *(const v4f*)(q0 + 4); v4f Wb1 = *(const v4f*)(q1 + 4);
    v4f Wa2 = *(const v4f*)(q0 + 8); v4f Wb2 = *(const v4f*)(q1 + 8);
    const float* p0 = q0 + 12;
    const float* p1 = q1 + 12;

    auto runblk = [&](bool ACC) {   // 8 steps + next-block prefetch
        const v4f Na1 = *(const v4f*)(p0); const v4f Na2 = *(const v4f*)(p0 + 4);
        const v4f Nb1 = *(const v4f*)(p1); const v4f Nb2 = *(const v4f*)(p1 + 4);
        step(Wa0.y, Wb0.y, ACC, true );
        step(Wa0.z, Wb0.z, ACC, false);
        step(Wa0.w, Wb0.w, ACC, false);
        step(Wa1.x, Wb1.x, ACC, false);
        step(Wa1.y, Wb1.y, ACC, false);
        step(Wa1.z, Wb1.z, ACC, false);
        step(Wa1.w, Wb1.w, ACC, false);
        step(Wa2.x, Wb2.x, ACC, false);
        Wa0 = Wa2; Wa1 = Na1; Wa2 = Na2;
        Wb0 = Wb2; Wb1 = Nb1; Wb2 = Nb2;
        p0 += 8; p1 += 8;
    };

#define BLK8_REGS(ACC) \
    step(Wa0.y, Wb0.y, ACC, true ); \
    step(Wa0.z, Wb0.z, ACC, false); \
    step(Wa0.w, Wb0.w, ACC, false); \
    step(Wa1.x, Wb1.x, ACC, false); \
    step(Wa1.y, Wb1.y, ACC, false); \
    step(Wa1.z, Wb1.z, ACC, false); \
    step(Wa1.w, Wb1.w, ACC, false); \
    step(Wa2.x, Wb2.x, ACC, false);

    float xt1 = 0.0f, xt2 = 0.0f;
    if (c == 0) {
        for (int g = 0; g < 59; ++g) runblk(true);    // acc t = 1..472
        BLK8_REGS(true)                                // acc t = 473..480
    } else {
        for (int g = 0; g < 58; ++g) runblk(false);   // warm t = t_s..t_s+463
        for (int g = 0; g < 12; ++g) runblk(true);    // acc blocks 58..69
        BLK8_REGS(true)                                // acc block 70
        if (c == 15) {
            // tail: t = 2041..2046, scalar in-bounds loads
            float fa[6], fb[6];
#pragma unroll
            for (int j = 0; j < 6; ++j) { fa[j] = rw0[2041+j]; fb[j] = rw1[2041+j]; }
            step(fa[0], fb[0], true,  true );
            step(fa[1], fb[1], true,  false);
            step(fa[2], fb[2], true,  false);
            step(fa[3], fb[3], true,  false);
            step(fa[4], fb[4], true,  false);
            step(fa[5], fb[5], false, false);   // t=2046: no acc
            xt1 = x1; xt2 = x2;                 // x_T
        }
    }

    // per-chunk partial cost -> ws[c][b]
    float P = SXX1 + SXX2 + SD;
    P = __builtin_fmaf(K0*K0, SXX1, P);
    P = __builtin_fmaf(2.0f*K0*K1, SXY, P);
    P = __builtin_fmaf(K1*K1, SXX2, P);
    if (c == 0)  P += 2.0f + K0*K0;                 // t=0 terms
    if (c == 15) P += 10.0f * (xt1*xt1 + xt2*xt2);  // final cost
    ws[c * 4096 + b] = P;
#undef BLK8_REGS
}

__global__ __launch_bounds__(64)
void cstr_reduce(const float* __restrict__ ws, float* __restrict__ out)
{
    const int b = blockIdx.x * 64 + threadIdx.x;   // 0..4095
    float s = 0.0f;
#pragma unroll
    for (int c = 0; c < 16; ++c) s += ws[c * 4096 + b];
    out[b] = s;
}

extern "C" void kernel_launch(void* const* d_in, const int* in_sizes, int n_in,
                              void* d_out, int out_size, void* d_ws, size_t ws_size,
                              hipStream_t stream) {
    const float* w  = (const float*)d_in[0];
    const float* K  = (const float*)d_in[1];
    const float* L  = (const float*)d_in[2];
    const float* M  = (const float*)d_in[3];
    const float* Mo = (const float*)d_in[4];
    float* out = (float*)d_out;
    float* ws  = (float*)d_ws;                     // 16*4096*4 B = 256 KB
    cstr_chunk <<<dim3(1024), dim3(64), 0, stream>>>(w, K, L, M, Mo, ws);
    cstr_reduce<<<dim3(64),   dim3(64), 0, stream>>>(ws, out);
}

// Round 14
// 60.470 us; speedup vs baseline: 4.6338x; 1.3695x over previous
//
#include <hip/hip_runtime.h>

#define NSTEP 2047

typedef float v4f __attribute__((ext_vector_type(4), aligned(4)));

__device__ __forceinline__ float fexp2(float x){float r;asm("v_exp_f32 %0, %1":"=v"(r):"v"(x));return r;}
__device__ __forceinline__ float frcp (float x){float r;asm("v_rcp_f32 %0, %1":"=v"(r):"v"(x));return r;}

// 16 chunks, W=320, window=112, XCD-affine block mapping (wgid = c*64+g).
// c=0: exact from t=1, acc t=1..368 (46 blocks). Cost 368.
// c=1..14: t_s=112c-63, warm 40 blocks, acc 14 blocks -> t in [112c+257, 112c+368]. Cost 432.
// c=15: t_s=1617, warm 40, acc 13 blocks (t=1937..2040) + peel t=2041..2045, then t=2046 -> x_T. Cost 430.
__global__ __launch_bounds__(64, 1)
void cstr_chunk(const float* __restrict__ w, const float* __restrict__ Kp,
                const float* __restrict__ Lp, const float* __restrict__ Mp,
                const float* __restrict__ Mop, float* __restrict__ ws)
{
    const int lane = threadIdx.x;
    const int wid  = blockIdx.x;               // 1024 waves
    const int c    = wid >> 6;                 // chunk 0..15 (wave-uniform)
    const int g    = wid & 63;                 // sample group; XCD = g%8 for ALL c
    const int b    = g * 64 + lane;            // sample 0..4095

    constexpr float Hc=0.01f, Acf=0.99f, Bcf=-0.5f*Hc*Hc;
    constexpr float T2L=2.8853900817779268f, L2E=1.4426950408889634f;
    constexpr float SC1=0.5f*Hc, SCT=SC1*T2L;

    const float K0=Kp[0], K1=Kp[1], MoV=Mop[0];
    const float c00=Lp[0], c11=Lp[5], c22=Lp[10], c33=Lp[15];
    const float c01=Lp[1]+Lp[4], c02=Lp[2]+Lp[8], c03=Lp[3]+Lp[12];
    const float c12=Lp[6]+Lp[9], c13=Lp[7]+Lp[13], c23=Lp[11]+Lp[14];
    const float m0=Mp[0], m1=Mp[1], m2=Mp[2], m3=Mp[3];
    const float sB = MoV * L2E;

    const int t_s = (c == 0) ? 1 : 112*c - 63;   // o0 = t_s-1 == 0 mod 8
    const int o0  = t_s - 1;

    const float* rw0 = w + (size_t)b * (2*NSTEP);
    const float* rw1 = rw0 + NSTEP;

    const float w10 = rw0[0], w20 = rw1[0];
    const float th1 = 1.0f - 2.0f*frcp(fexp2(T2L) + 1.0f);   // tanh(1)

    // ---- state init ----
    float x1, x2, xh1, U, THh1;
    if (c == 0) {
        x1 = Acf + Hc*SC1 + Hc*K0 + w10;
        x2 = Bcf - Hc*th1 + 0.5f*Hc*K0 + w20;
        xh1 = 1.0f; U = K0; THh1 = th1;
    } else { x1 = 0.0f; x2 = 0.0f; xh1 = 0.0f; U = 0.0f; THh1 = 0.0f; }
    float xh2 = 0.0f;
    float THh2 = 1.0f - 2.0f*frcp(fexp2(SCT) + 1.0f);
    float THx1 = 1.0f - 2.0f*frcp(fexp2(T2L*x1) + 1.0f);
    float THx2 = 1.0f - 2.0f*frcp(fexp2(__builtin_fmaf(T2L,x2,SCT)) + 1.0f);
    float delta = 0.5f, PS = 0.0f;
    float SXX1=0.0f, SXX2=0.0f, SXY=0.0f, SD=0.0f;

    auto step = [&](float w1v, float w2v, bool acc, bool exact) {
        const float hu = Hc*U;
        const float f1 = __builtin_fmaf(Acf, xh1, __builtin_fmaf(Hc, THh2, hu));
        const float f2 = __builtin_fmaf(Acf, xh2, __builtin_fmaf(-Hc, THh1,
                          __builtin_fmaf(0.5f, hu, Bcf)));
        float g1 = __builtin_fmaf(c00,x1,m0); g1=__builtin_fmaf(c01,x2,g1);
        g1=__builtin_fmaf(c02,f1,g1); g1=__builtin_fmaf(c03,f2,g1);
        float g2 = __builtin_fmaf(c11,x2,m1); g2=__builtin_fmaf(c12,f1,g2);
        g2=__builtin_fmaf(c13,f2,g2);
        float g3 = __builtin_fmaf(c22,f1,m2); g3=__builtin_fmaf(c23,f2,g3);
        float g4 = __builtin_fmaf(c33,f2,m3);
        const float ps = __builtin_fmaf(x1,g1, __builtin_fmaf(x2,g2,
                          __builtin_fmaf(f1,g3, f2*g4)));
        if (exact) {
            delta = frcp(1.0f + fexp2(__builtin_fmaf(-L2E, ps, -sB)));
        } else {
            const float dphi = ps - PS;
            const float sd = __builtin_fmaf(-delta, delta, delta);
            const float qq = __builtin_fmaf(dphi, 0.5f - delta, 1.0f);
            delta = __builtin_fmaf(dphi*sd, qq, delta);
        }
        PS = ps;
        const float d1 = x1 - f1, d2 = x2 - f2;
        const float nh1 = __builtin_fmaf(delta, d1, f1);
        const float nh2 = __builtin_fmaf(delta, d2, f2);
        const float un  = __builtin_fmaf(K1, nh2, K0*nh1);
        if (acc) {
            SXX1 = __builtin_fmaf(x1, x1, SXX1);
            SXX2 = __builtin_fmaf(x2, x2, SXX2);
            SXY  = __builtin_fmaf(x1, x2, SXY);
            SD  += delta;
        }
        const float hun = Hc*un;
        const float nx1 = __builtin_fmaf(Acf, x1, __builtin_fmaf(Hc, THx2, w1v + hun));
        const float nx2 = __builtin_fmaf(Acf, x2, __builtin_fmaf(-Hc, THx1,
                           __builtin_fmaf(0.5f, hun, w2v + Bcf)));
        if (exact) {
            THh1 = __builtin_fmaf(-2.0f, frcp(fexp2(T2L*nh1)+1.0f), 1.0f);
            THh2 = __builtin_fmaf(-2.0f, frcp(fexp2(__builtin_fmaf(T2L,nh2,SCT))+1.0f), 1.0f);
            THx1 = __builtin_fmaf(-2.0f, frcp(fexp2(T2L*nx1)+1.0f), 1.0f);
            THx2 = __builtin_fmaf(-2.0f, frcp(fexp2(__builtin_fmaf(T2L,nx2,SCT))+1.0f), 1.0f);
        } else {
            { const float dS=nh1-xh1, sc=__builtin_fmaf(-THh1,THh1,1.0f);
              THh1=__builtin_fmaf(dS*sc, __builtin_fmaf(-dS,THh1,1.0f), THh1); }
            { const float dS=nh2-xh2, sc=__builtin_fmaf(-THh2,THh2,1.0f);
              THh2=__builtin_fmaf(dS*sc, __builtin_fmaf(-dS,THh2,1.0f), THh2); }
            { const float dS=nx1-x1,  sc=__builtin_fmaf(-THx1,THx1,1.0f);
              THx1=__builtin_fmaf(dS*sc, __builtin_fmaf(-dS,THx1,1.0f), THx1); }
            { const float dS=nx2-x2,  sc=__builtin_fmaf(-THx2,THx2,1.0f);
              THx2=__builtin_fmaf(dS*sc, __builtin_fmaf(-dS,THx2,1.0f), THx2); }
        }
        x1=nx1; x2=nx2; xh1=nh1; xh2=nh2; U=un;
    };

    // ---- rolling 16B float4 stream: regs hold words [o..o+11], advance 8 ----
    const float* q0 = rw0 + o0;
    const float* q1 = rw1 + o0;
    v4f Wa0 = *(const v4f*)(q0);     v4f Wb0 = *(const v4f*)(q1);
    v4f Wa1 = *(const v4f*)(q0 + 4); v4f Wb1 = *(const v4f*)(q1 + 4);
    v4f Wa2 = *(const v4f*)(q0 + 8); v4f Wb2 = *(const v4f*)(q1 + 8);
    const float* p0 = q0 + 12;
    const float* p1 = q1 + 12;

    auto runblk = [&](bool ACC) {   // 8 steps + next-block prefetch
        const v4f Na1 = *(const v4f*)(p0); const v4f Na2 = *(const v4f*)(p0 + 4);
        const v4f Nb1 = *(const v4f*)(p1); const v4f Nb2 = *(const v4f*)(p1 + 4);
        step(Wa0.y, Wb0.y, ACC, true );
        step(Wa0.z, Wb0.z, ACC, false);
        step(Wa0.w, Wb0.w, ACC, false);
        step(Wa1.x, Wb1.x, ACC, false);
        step(Wa1.y, Wb1.y, ACC, false);
        step(Wa1.z, Wb1.z, ACC, false);
        step(Wa1.w, Wb1.w, ACC, false);
        step(Wa2.x, Wb2.x, ACC, false);
        Wa0 = Wa2; Wa1 = Na1; Wa2 = Na2;
        Wb0 = Wb2; Wb1 = Nb1; Wb2 = Nb2;
        p0 += 8; p1 += 8;
    };

#define BLK8_REGS(ACC) \
    step(Wa0.y, Wb0.y, ACC, true ); \
    step(Wa0.z, Wb0.z, ACC, false); \
    step(Wa0.w, Wb0.w, ACC, false); \
    step(Wa1.x, Wb1.x, ACC, false); \
    step(Wa1.y, Wb1.y, ACC, false); \
    step(Wa1.z, Wb1.z, ACC, false); \
    step(Wa1.w, Wb1.w, ACC, false); \
    step(Wa2.x, Wb2.x, ACC, false);

    float xt1 = 0.0f, xt2 = 0.0f;
    if (c == 0) {
        for (int k = 0; k < 45; ++k) runblk(true);    // acc t = 1..360
        BLK8_REGS(true)                                // acc t = 361..368
    } else if (c <= 14) {
        for (int k = 0; k < 40; ++k) runblk(false);   // warm t = t_s..t_s+319
        for (int k = 0; k < 14; ++k) runblk(true);    // acc t in [112c+257, 112c+368]
    } else {  // c == 15, t_s = 1617
        for (int k = 0; k < 40; ++k) runblk(false);   // warm t = 1617..1936
        for (int k = 0; k < 12; ++k) runblk(true);    // acc t = 1937..2032
        BLK8_REGS(true)                                // acc t = 2033..2040
        // peel t = 2041..2046 (scalar, in-bounds)
        float fa[6], fb[6];
#pragma unroll
        for (int j = 0; j < 6; ++j) { fa[j] = rw0[2041+j]; fb[j] = rw1[2041+j]; }
        step(fa[0], fb[0], true,  true );
        step(fa[1], fb[1], true,  false);
        step(fa[2], fb[2], true,  false);
        step(fa[3], fb[3], true,  false);
        step(fa[4], fb[4], true,  false);
        step(fa[5], fb[5], false, false);   // t=2046: no acc
        xt1 = x1; xt2 = x2;                 // x_T
    }

    // per-chunk partial cost -> ws[c][b]
    float P = SXX1 + SXX2 + SD;
    P = __builtin_fmaf(K0*K0, SXX1, P);
    P = __builtin_fmaf(2.0f*K0*K1, SXY, P);
    P = __builtin_fmaf(K1*K1, SXX2, P);
    if (c == 0)  P += 2.0f + K0*K0;                 // t=0 terms
    if (c == 15) P += 10.0f * (xt1*xt1 + xt2*xt2);  // final cost
    ws[c * 4096 + b] = P;
#undef BLK8_REGS
}

__global__ __launch_bounds__(64)
void cstr_reduce(const float* __restrict__ ws, float* __restrict__ out)
{
    const int b = blockIdx.x * 64 + threadIdx.x;   // 0..4095
    float s = 0.0f;
#pragma unroll
    for (int c = 0; c < 16; ++c) s += ws[c * 4096 + b];
    out[b] = s;
}

extern "C" void kernel_launch(void* const* d_in, const int* in_sizes, int n_in,
                              void* d_out, int out_size, void* d_ws, size_t ws_size,
                              hipStream_t stream) {
    const float* w  = (const float*)d_in[0];
    const float* K  = (const float*)d_in[1];
    const float* L  = (const float*)d_in[2];
    const float* M  = (const float*)d_in[3];
    const float* Mo = (const float*)d_in[4];
    float* out = (float*)d_out;
    float* ws  = (float*)d_ws;                     // 16*4096*4 B = 256 KB
    cstr_chunk <<<dim3(1024), dim3(64), 0, stream>>>(w, K, L, M, Mo, ws);
    cstr_reduce<<<dim3(64),   dim3(64), 0, stream>>>(ws, out);
}

// Round 15
// 52.344 us; speedup vs baseline: 5.3532x; 1.1553x over previous
//
#include <hip/hip_runtime.h>

#define NSTEP 2047

typedef float v4f __attribute__((ext_vector_type(4), aligned(4)));

__device__ __forceinline__ float fexp2(float x){float r;asm("v_exp_f32 %0, %1":"=v"(r):"v"(x));return r;}
__device__ __forceinline__ float frcp (float x){float r;asm("v_rcp_f32 %0, %1":"=v"(r):"v"(x));return r;}

// 16 chunks, W=256, window=112, perfectly balanced (368 steps/wave),
// XCD-affine mapping (wid = c*64+g -> XCD g%8 for all chunks of group g).
// c=0: exact from t=1, acc t=1..368 (46 blocks).
// c=1..14: t_s=112c+1, warm 32 blocks, acc 14 -> t in [112c+257, 112c+368].
// c=15: t_s=1681, warm 32, acc t=1937..2045, then t=2046 (no acc) -> x_T.
__global__ __launch_bounds__(64, 1)
void cstr_chunk(const float* __restrict__ w, const float* __restrict__ Kp,
                const float* __restrict__ Lp, const float* __restrict__ Mp,
                const float* __restrict__ Mop, float* __restrict__ ws)
{
    const int lane = threadIdx.x;
    const int wid  = blockIdx.x;               // 1024 waves
    const int c    = wid >> 6;                 // chunk 0..15 (wave-uniform)
    const int g    = wid & 63;                 // sample group
    const int b    = g * 64 + lane;            // sample 0..4095

    constexpr float Hc=0.01f, Acf=0.99f, Bcf=-0.5f*Hc*Hc;
    constexpr float T2L=2.8853900817779268f, L2E=1.4426950408889634f;
    constexpr float SC1=0.5f*Hc, SCT=SC1*T2L;

    const float K0=Kp[0], K1=Kp[1], MoV=Mop[0];
    const float c00=Lp[0], c11=Lp[5], c22=Lp[10], c33=Lp[15];
    const float c01=Lp[1]+Lp[4], c02=Lp[2]+Lp[8], c03=Lp[3]+Lp[12];
    const float c12=Lp[6]+Lp[9], c13=Lp[7]+Lp[13], c23=Lp[11]+Lp[14];
    const float m0=Mp[0], m1=Mp[1], m2=Mp[2], m3=Mp[3];
    const float sB = MoV * L2E;

    const int t_s = (c == 0) ? 1 : 112*c + 1;    // o0 = t_s-1 = 112c == 0 mod 8
    const int o0  = t_s - 1;

    const float* rw0 = w + (size_t)b * (2*NSTEP);
    const float* rw1 = rw0 + NSTEP;

    const float w10 = rw0[0], w20 = rw1[0];
    const float th1 = 1.0f - 2.0f*frcp(fexp2(T2L) + 1.0f);   // tanh(1)

    // ---- state init ----
    float x1, x2, xh1, U, THh1;
    if (c == 0) {
        x1 = Acf + Hc*SC1 + Hc*K0 + w10;
        x2 = Bcf - Hc*th1 + 0.5f*Hc*K0 + w20;
        xh1 = 1.0f; U = K0; THh1 = th1;
    } else { x1 = 0.0f; x2 = 0.0f; xh1 = 0.0f; U = 0.0f; THh1 = 0.0f; }
    float xh2 = 0.0f;
    float THh2 = 1.0f - 2.0f*frcp(fexp2(SCT) + 1.0f);
    float THx1 = 1.0f - 2.0f*frcp(fexp2(T2L*x1) + 1.0f);
    float THx2 = 1.0f - 2.0f*frcp(fexp2(__builtin_fmaf(T2L,x2,SCT)) + 1.0f);
    float delta = 0.5f, PS = 0.0f;
    float SXX1=0.0f, SXX2=0.0f, SXY=0.0f, SD=0.0f;

    auto step = [&](float w1v, float w2v, bool acc, bool exact) {
        const float hu = Hc*U;
        const float f1 = __builtin_fmaf(Acf, xh1, __builtin_fmaf(Hc, THh2, hu));
        const float f2 = __builtin_fmaf(Acf, xh2, __builtin_fmaf(-Hc, THh1,
                          __builtin_fmaf(0.5f, hu, Bcf)));
        float g1 = __builtin_fmaf(c00,x1,m0); g1=__builtin_fmaf(c01,x2,g1);
        g1=__builtin_fmaf(c02,f1,g1); g1=__builtin_fmaf(c03,f2,g1);
        float g2 = __builtin_fmaf(c11,x2,m1); g2=__builtin_fmaf(c12,f1,g2);
        g2=__builtin_fmaf(c13,f2,g2);
        float g3 = __builtin_fmaf(c22,f1,m2); g3=__builtin_fmaf(c23,f2,g3);
        float g4 = __builtin_fmaf(c33,f2,m3);
        const float ps = __builtin_fmaf(x1,g1, __builtin_fmaf(x2,g2,
                          __builtin_fmaf(f1,g3, f2*g4)));
        if (exact) {
            delta = frcp(1.0f + fexp2(__builtin_fmaf(-L2E, ps, -sB)));
        } else {  // 2nd-order sigmoid propagation (feeds SD directly)
            const float dphi = ps - PS;
            const float sd = __builtin_fmaf(-delta, delta, delta);
            const float qq = __builtin_fmaf(dphi, 0.5f - delta, 1.0f);
            delta = __builtin_fmaf(dphi*sd, qq, delta);
        }
        PS = ps;
        const float d1 = x1 - f1, d2 = x2 - f2;
        const float nh1 = __builtin_fmaf(delta, d1, f1);
        const float nh2 = __builtin_fmaf(delta, d2, f2);
        const float un  = __builtin_fmaf(K1, nh2, K0*nh1);
        if (acc) {
            SXX1 = __builtin_fmaf(x1, x1, SXX1);
            SXX2 = __builtin_fmaf(x2, x2, SXX2);
            SXY  = __builtin_fmaf(x1, x2, SXY);
            SD  += delta;
        }
        const float hun = Hc*un;
        const float nx1 = __builtin_fmaf(Acf, x1, __builtin_fmaf(Hc, THx2, w1v + hun));
        const float nx2 = __builtin_fmaf(Acf, x2, __builtin_fmaf(-Hc, THx1,
                           __builtin_fmaf(0.5f, hun, w2v + Bcf)));
        if (exact) {
            THh1 = __builtin_fmaf(-2.0f, frcp(fexp2(T2L*nh1)+1.0f), 1.0f);
            THh2 = __builtin_fmaf(-2.0f, frcp(fexp2(__builtin_fmaf(T2L,nh2,SCT))+1.0f), 1.0f);
            THx1 = __builtin_fmaf(-2.0f, frcp(fexp2(T2L*nx1)+1.0f), 1.0f);
            THx2 = __builtin_fmaf(-2.0f, frcp(fexp2(__builtin_fmaf(T2L,nx2,SCT))+1.0f), 1.0f);
        } else {  // 1st-order tanh propagation: TH += dS*(1-TH^2); error*H<=1e-5/step
            { const float dS=nh1-xh1, sc=__builtin_fmaf(-THh1,THh1,1.0f);
              THh1=__builtin_fmaf(dS, sc, THh1); }
            { const float dS=nh2-xh2, sc=__builtin_fmaf(-THh2,THh2,1.0f);
              THh2=__builtin_fmaf(dS, sc, THh2); }
            { const float dS=nx1-x1,  sc=__builtin_fmaf(-THx1,THx1,1.0f);
              THx1=__builtin_fmaf(dS, sc, THx1); }
            { const float dS=nx2-x2,  sc=__builtin_fmaf(-THx2,THx2,1.0f);
              THx2=__builtin_fmaf(dS, sc, THx2); }
        }
        x1=nx1; x2=nx2; xh1=nh1; xh2=nh2; U=un;
    };

    // ---- rolling 16B float4 stream: regs hold words [o..o+11], advance 8 ----
    const float* q0 = rw0 + o0;
    const float* q1 = rw1 + o0;
    v4f Wa0 = *(const v4f*)(q0);     v4f Wb0 = *(const v4f*)(q1);
    v4f Wa1 = *(const v4f*)(q0 + 4); v4f Wb1 = *(const v4f*)(q1 + 4);
    v4f Wa2 = *(const v4f*)(q0 + 8); v4f Wb2 = *(const v4f*)(q1 + 8);
    const float* p0 = q0 + 12;
    const float* p1 = q1 + 12;

    auto runblk = [&](bool ACC) {   // 8 steps + next-block prefetch
        const v4f Na1 = *(const v4f*)(p0); const v4f Na2 = *(const v4f*)(p0 + 4);
        const v4f Nb1 = *(const v4f*)(p1); const v4f Nb2 = *(const v4f*)(p1 + 4);
        step(Wa0.y, Wb0.y, ACC, true );
        step(Wa0.z, Wb0.z, ACC, false);
        step(Wa0.w, Wb0.w, ACC, false);
        step(Wa1.x, Wb1.x, ACC, false);
        step(Wa1.y, Wb1.y, ACC, false);
        step(Wa1.z, Wb1.z, ACC, false);
        step(Wa1.w, Wb1.w, ACC, false);
        step(Wa2.x, Wb2.x, ACC, false);
        Wa0 = Wa2; Wa1 = Na1; Wa2 = Na2;
        Wb0 = Wb2; Wb1 = Nb1; Wb2 = Nb2;
        p0 += 8; p1 += 8;
    };

#define BLK8_REGS(ACC) \
    step(Wa0.y, Wb0.y, ACC, true ); \
    step(Wa0.z, Wb0.z, ACC, false); \
    step(Wa0.w, Wb0.w, ACC, false); \
    step(Wa1.x, Wb1.x, ACC, false); \
    step(Wa1.y, Wb1.y, ACC, false); \
    step(Wa1.z, Wb1.z, ACC, false); \
    step(Wa1.w, Wb1.w, ACC, false); \
    step(Wa2.x, Wb2.x, ACC, false);

    float xt1 = 0.0f, xt2 = 0.0f;
    if (c == 0) {
        for (int k = 0; k < 45; ++k) runblk(true);    // acc t = 1..360
        BLK8_REGS(true)                                // acc t = 361..368
    } else if (c <= 14) {
        for (int k = 0; k < 32; ++k) runblk(false);   // warm t = t_s..t_s+255
        for (int k = 0; k < 14; ++k) runblk(true);    // acc t in [112c+257, 112c+368]
    } else {  // c == 15, t_s = 1681
        for (int k = 0; k < 32; ++k) runblk(false);   // warm t = 1681..1936
        for (int k = 0; k < 12; ++k) runblk(true);    // acc t = 1937..2032
        BLK8_REGS(true)                                // acc t = 2033..2040
        // peel t = 2041..2046 (scalar, in-bounds)
        float fa[6], fb[6];
#pragma unroll
        for (int j = 0; j < 6; ++j) { fa[j] = rw0[2041+j]; fb[j] = rw1[2041+j]; }
        step(fa[0], fb[0], true,  true );
        step(fa[1], fb[1], true,  false);
        step(fa[2], fb[2], true,  false);
        step(fa[3], fb[3], true,  false);
        step(fa[4], fb[4], true,  false);
        step(fa[5], fb[5], false, false);   // t=2046: no acc
        xt1 = x1; xt2 = x2;                 // x_T
    }

    // per-chunk partial cost -> ws[c][b]
    float P = SXX1 + SXX2 + SD;
    P = __builtin_fmaf(K0*K0, SXX1, P);
    P = __builtin_fmaf(2.0f*K0*K1, SXY, P);
    P = __builtin_fmaf(K1*K1, SXX2, P);
    if (c == 0)  P += 2.0f + K0*K0;                 // t=0 terms
    if (c == 15) P += 10.0f * (xt1*xt1 + xt2*xt2);  // final cost
    ws[c * 4096 + b] = P;
#undef BLK8_REGS
}

__global__ __launch_bounds__(64)
void cstr_reduce(const float* __restrict__ ws, float* __restrict__ out)
{
    const int b = blockIdx.x * 64 + threadIdx.x;   // 0..4095
    float s = 0.0f;
#pragma unroll
    for (int c = 0; c < 16; ++c) s += ws[c * 4096 + b];
    out[b] = s;
}

extern "C" void kernel_launch(void* const* d_in, const int* in_sizes, int n_in,
                              void* d_out, int out_size, void* d_ws, size_t ws_size,
                              hipStream_t stream) {
    const float* w  = (const float*)d_in[0];
    const float* K  = (const float*)d_in[1];
    const float* L  = (const float*)d_in[2];
    const float* M  = (const float*)d_in[3];
    const float* Mo = (const float*)d_in[4];
    float* out = (float*)d_out;
    float* ws  = (float*)d_ws;                     // 16*4096*4 B = 256 KB
    cstr_chunk <<<dim3(1024), dim3(64), 0, stream>>>(w, K, L, M, Mo, ws);
    cstr_reduce<<<dim3(64),   dim3(64), 0, stream>>>(ws, out);
}